// Round 1
// baseline (69.964 us; speedup 1.0000x reference)
//
#include <hip/hip_runtime.h>
#include <math.h>

// DegradedBicycleRollout: b=512, l=64, h=80, state=12.
// One thread per (b,l) rollout; serial over h (lax.scan dependence).
// controls [b,l,h,3] -> per-thread contiguous 240 floats (960B, 16B aligned).
// out [b,l,h+1,12]   -> per-thread contiguous 972 floats; 3x float4 per step.

#define N_B 512
#define N_L 64
#define N_H 80
#define DT_F 0.1f
#define WHEELBASE_F 2.8f

__global__ __launch_bounds__(64) void degraded_bicycle_rollout_kernel(
    const float* __restrict__ x0,        // [512,12]
    const float* __restrict__ controls,  // [512,64,80,3]
    const float* __restrict__ deg,       // [512,5]
    float* __restrict__ out)             // [512,64,81,12]
{
    const int tid = blockIdx.x * 64 + threadIdx.x;   // rollout id = b*64 + l
    const int b = tid >> 6;

    const float* dg = deg + b * 5;
    const float steer_scale    = fmaxf(dg[0], 0.05f);
    const float brake_scale    = fmaxf(dg[1], 0.05f);
    const float throttle_scale = fmaxf(dg[2], 0.05f);
    const float friction       = fmaxf(dg[4], 0.1f);

    // x_init: full 12-dim x0 row (16B-aligned: b*12 floats = 48B multiple)
    const float4* x0v = reinterpret_cast<const float4*>(x0 + b * 12);
    const float4 xi0 = x0v[0];
    const float4 xi1 = x0v[1];
    const float4 xi2 = x0v[2];

    float* o = out + (size_t)tid * 972;   // 81*12 floats per rollout
    {
        float4* ov = reinterpret_cast<float4*>(o);
        ov[0] = xi0; ov[1] = xi1; ov[2] = xi2;   // h = 0 row
    }

    float px  = xi0.x;
    float py  = xi0.y;
    float psi = xi0.z;
    float vx  = xi0.w;
    float vy  = xi1.x;

    // per-thread controls: 240 floats contiguous, base = tid*960 B (16B aligned)
    const float4* uc = reinterpret_cast<const float4*>(controls + (size_t)tid * 240);

    const float neg_brake_lim = -7.5f * friction;
    const float yaw_num = friction * 9.81f;

    for (int hb = 0; hb < N_H / 4; ++hb) {
        // 4 steps worth of controls = 12 floats = 3 float4 (fully coalescable)
        const float4 c0 = uc[hb * 3 + 0];
        const float4 c1 = uc[hb * 3 + 1];
        const float4 c2 = uc[hb * 3 + 2];
        const float us[12] = {c0.x, c0.y, c0.z, c0.w,
                              c1.x, c1.y, c1.z, c1.w,
                              c2.x, c2.y, c2.z, c2.w};
        #pragma unroll
        for (int j = 0; j < 4; ++j) {
            const float u0 = us[j * 3 + 0];
            const float u1 = us[j * 3 + 1];
            const float u2 = us[j * 3 + 2];

            // control transforms (state-independent -> ILP ahead of the chain)
            const float delta = steer_scale * tanhf(u0);
            const float fb = brake_scale    * (1.0f / (1.0f + expf(-u1)));
            const float fx = throttle_scale * (1.0f / (1.0f + expf(-u2)));
            const float tan_d = tanf(fminf(fmaxf(delta, -0.75f), 0.75f));
            const float beta = fminf(fmaxf(atanf(0.45f * tan_d), -0.65f), 0.65f);
            const float acc = fminf(fmaxf(2.8f * fx - 6.5f * fb, neg_brake_lim), 3.0f);

            // serial state chain
            const float speed  = sqrtf(vx * vx + vy * vy + 1e-6f);
            const float speed2 = fmaxf(speed + acc * DT_F, 0.0f);
            const float raw_yaw = speed2 / WHEELBASE_F * tan_d;
            const float yaw_lim = fmaxf(yaw_num / fmaxf(speed2, 2.0f), 0.15f);
            const float yaw_rate = fminf(fmaxf(raw_yaw, -1.0f), 1.0f) * yaw_lim;
            const float psi2 = psi + yaw_rate * DT_F;
            float s, c;
            sincosf(psi2 + beta, &s, &c);
            const float vx2 = speed2 * c;
            const float vy2 = speed2 * s;
            const float px2 = px + vx2 * DT_F;
            const float py2 = py + vy2 * DT_F;
            const float ax = (vx2 - vx) / DT_F;
            const float ay = (vy2 - vy) / DT_F;

            const int h = hb * 4 + j;
            float4* wp = reinterpret_cast<float4*>(o + (size_t)(h + 1) * 12);
            wp[0] = make_float4(px2, py2, psi2, vx2);
            wp[1] = make_float4(vy2, yaw_rate, ax, ay);
            wp[2] = make_float4(beta, delta, fb, fx);

            px = px2; py = py2; psi = psi2; vx = vx2; vy = vy2;
        }
    }
}

extern "C" void kernel_launch(void* const* d_in, const int* in_sizes, int n_in,
                              void* d_out, int out_size, void* d_ws, size_t ws_size,
                              hipStream_t stream) {
    (void)in_sizes; (void)n_in; (void)d_ws; (void)ws_size; (void)out_size;
    const float* x0       = (const float*)d_in[0];
    const float* controls = (const float*)d_in[1];
    const float* deg      = (const float*)d_in[2];
    float* out            = (float*)d_out;

    const int total = N_B * N_L;            // 32768 rollouts
    dim3 grid(total / 64), block(64);       // 512 blocks x 1 wave
    hipLaunchKernelGGL(degraded_bicycle_rollout_kernel, grid, block, 0, stream,
                       x0, controls, deg, out);
}

// Round 2
// 66.045 us; speedup vs baseline: 1.0593x; 1.0593x over previous
//
#include <hip/hip_runtime.h>
#include <math.h>

// DegradedBicycleRollout: b=512, l=64, h=80, state=12.
// One thread per (b,l) rollout; serial over h (lax.scan dependence).
// R2: libm -> native HW intrinsics (v_exp/v_sin/v_cos/v_rcp/v_sqrt + atan poly).
// R1 post-mortem: 84us = ~2500 cyc/step was libm software routines, not the
// ~150-cycle dependence chain. Occupancy is structurally 512 waves.

#define N_B 512
#define N_L 64
#define N_H 80
#define DT_F 0.1f

__device__ __forceinline__ float fast_rcp(float x) {
    return __builtin_amdgcn_rcpf(x);
}

__device__ __forceinline__ float fast_tanh(float x) {
    // |x| <= ~6 for N(0,1) inputs; e2 stays finite.
    const float e2 = __expf(2.0f * x);
    return (e2 - 1.0f) * fast_rcp(e2 + 1.0f);
}

__device__ __forceinline__ float fast_sigmoid(float x) {
    return fast_rcp(1.0f + __expf(-x));
}

__device__ __forceinline__ float fast_atan_small(float z) {
    // |z| <= 0.45 (z = 0.45*tan(clip(delta,+-0.75)) -> |z| <= 0.4192).
    // Odd Taylor through z^9: max err ~1e-5 on this range.
    const float z2 = z * z;
    float p = 1.0f / 9.0f;
    p = fmaf(p, z2, -1.0f / 7.0f);
    p = fmaf(p, z2, 1.0f / 5.0f);
    p = fmaf(p, z2, -1.0f / 3.0f);
    p = fmaf(p, z2, 1.0f);
    return z * p;
}

__global__ __launch_bounds__(64) void degraded_bicycle_rollout_kernel(
    const float* __restrict__ x0,        // [512,12]
    const float* __restrict__ controls,  // [512,64,80,3]
    const float* __restrict__ deg,       // [512,5]
    float* __restrict__ out)             // [512,64,81,12]
{
    const int tid = blockIdx.x * 64 + threadIdx.x;   // rollout id = b*64 + l
    const int b = tid >> 6;

    const float* dg = deg + b * 5;
    const float steer_scale    = fmaxf(dg[0], 0.05f);
    const float brake_scale    = fmaxf(dg[1], 0.05f);
    const float throttle_scale = fmaxf(dg[2], 0.05f);
    const float friction       = fmaxf(dg[4], 0.1f);

    const float4* x0v = reinterpret_cast<const float4*>(x0 + b * 12);
    const float4 xi0 = x0v[0];
    const float4 xi1 = x0v[1];
    const float4 xi2 = x0v[2];

    float* o = out + (size_t)tid * 972;   // 81*12 floats per rollout
    {
        float4* ov = reinterpret_cast<float4*>(o);
        ov[0] = xi0; ov[1] = xi1; ov[2] = xi2;   // h = 0 row
    }

    float px  = xi0.x;
    float py  = xi0.y;
    float psi = xi0.z;
    float vx  = xi0.w;
    float vy  = xi1.x;

    const float4* uc = reinterpret_cast<const float4*>(controls + (size_t)tid * 240);

    const float neg_brake_lim = -7.5f * friction;
    const float yaw_num = friction * 9.81f;
    const float inv_wheelbase = 1.0f / 2.8f;

    for (int hb = 0; hb < N_H / 4; ++hb) {
        const float4 c0 = uc[hb * 3 + 0];
        const float4 c1 = uc[hb * 3 + 1];
        const float4 c2 = uc[hb * 3 + 2];
        const float us[12] = {c0.x, c0.y, c0.z, c0.w,
                              c1.x, c1.y, c1.z, c1.w,
                              c2.x, c2.y, c2.z, c2.w};
        #pragma unroll
        for (int j = 0; j < 4; ++j) {
            const float u0 = us[j * 3 + 0];
            const float u1 = us[j * 3 + 1];
            const float u2 = us[j * 3 + 2];

            // state-independent control transforms (off the serial chain)
            const float delta = steer_scale * fast_tanh(u0);
            const float fb = brake_scale    * fast_sigmoid(u1);
            const float fx = throttle_scale * fast_sigmoid(u2);
            const float dc = fminf(fmaxf(delta, -0.75f), 0.75f);
            float sd, cd;
            __sincosf(dc, &sd, &cd);
            const float tan_d = sd * fast_rcp(cd);        // |dc|<=0.75, cd>=0.73
            const float beta = fminf(fmaxf(fast_atan_small(0.45f * tan_d), -0.65f), 0.65f);
            const float acc = fminf(fmaxf(2.8f * fx - 6.5f * fb, neg_brake_lim), 3.0f);

            // serial state chain
            const float speed  = __builtin_amdgcn_sqrtf(fmaf(vx, vx, fmaf(vy, vy, 1e-6f)));
            const float speed2 = fmaxf(fmaf(acc, DT_F, speed), 0.0f);
            const float raw_yaw = speed2 * inv_wheelbase * tan_d;
            const float yaw_lim = fmaxf(yaw_num * fast_rcp(fmaxf(speed2, 2.0f)), 0.15f);
            const float yaw_rate = fminf(fmaxf(raw_yaw, -1.0f), 1.0f) * yaw_lim;
            const float psi2 = fmaf(yaw_rate, DT_F, psi);
            float s, c;
            __sincosf(psi2 + beta, &s, &c);
            const float vx2 = speed2 * c;
            const float vy2 = speed2 * s;
            const float px2 = fmaf(vx2, DT_F, px);
            const float py2 = fmaf(vy2, DT_F, py);
            const float ax = (vx2 - vx) * 10.0f;
            const float ay = (vy2 - vy) * 10.0f;

            const int h = hb * 4 + j;
            float4* wp = reinterpret_cast<float4*>(o + (size_t)(h + 1) * 12);
            wp[0] = make_float4(px2, py2, psi2, vx2);
            wp[1] = make_float4(vy2, yaw_rate, ax, ay);
            wp[2] = make_float4(beta, delta, fb, fx);

            px = px2; py = py2; psi = psi2; vx = vx2; vy = vy2;
        }
    }
}

extern "C" void kernel_launch(void* const* d_in, const int* in_sizes, int n_in,
                              void* d_out, int out_size, void* d_ws, size_t ws_size,
                              hipStream_t stream) {
    (void)in_sizes; (void)n_in; (void)d_ws; (void)ws_size; (void)out_size;
    const float* x0       = (const float*)d_in[0];
    const float* controls = (const float*)d_in[1];
    const float* deg      = (const float*)d_in[2];
    float* out            = (float*)d_out;

    const int total = N_B * N_L;            // 32768 rollouts
    dim3 grid(total / 64), block(64);       // 512 blocks x 1 wave each
    hipLaunchKernelGGL(degraded_bicycle_rollout_kernel, grid, block, 0, stream,
                       x0, controls, deg, out);
}

// Round 3
// 65.986 us; speedup vs baseline: 1.0603x; 1.0009x over previous
//
#include <hip/hip_runtime.h>
#include <math.h>

// DegradedBicycleRollout: b=512, l=64, h=80, state=12.
// One thread per (b,l) rollout; serial over h (lax.scan dependence).
// R3: (1) software-pipeline control loads by one 4-step group so vmcnt waits
//     never drain the uncoalesced store queue; (2) no indexable local arrays
//     (R2's VGPR=24 suggested scratch); (3) batch all 4 steps' state-independent
//     transforms ahead of the serial chain for ILP at 0.5 waves/SIMD.

#define N_B 512
#define N_L 64
#define N_H 80
#define DT_F 0.1f

__device__ __forceinline__ float fast_rcp(float x) { return __builtin_amdgcn_rcpf(x); }

__device__ __forceinline__ float fast_tanh(float x) {
    const float e2 = __expf(2.0f * x);
    return (e2 - 1.0f) * fast_rcp(e2 + 1.0f);
}

__device__ __forceinline__ float fast_sigmoid(float x) {
    return fast_rcp(1.0f + __expf(-x));
}

__device__ __forceinline__ float fast_atan_small(float z) {
    // |z| <= 0.42 here; odd Taylor through z^9, max err ~1e-5.
    const float z2 = z * z;
    float p = 1.0f / 9.0f;
    p = fmaf(p, z2, -1.0f / 7.0f);
    p = fmaf(p, z2, 1.0f / 5.0f);
    p = fmaf(p, z2, -1.0f / 3.0f);
    p = fmaf(p, z2, 1.0f);
    return z * p;
}

struct Ctl { float delta, fb, fx, tan_d, beta, acc; };

__device__ __forceinline__ Ctl make_ctl(float u0, float u1, float u2,
                                        float steer_scale, float brake_scale,
                                        float throttle_scale, float neg_brake_lim) {
    Ctl t;
    t.delta = steer_scale * fast_tanh(u0);
    t.fb = brake_scale    * fast_sigmoid(u1);
    t.fx = throttle_scale * fast_sigmoid(u2);
    const float dc = fminf(fmaxf(t.delta, -0.75f), 0.75f);
    float sd, cd;
    __sincosf(dc, &sd, &cd);
    t.tan_d = sd * fast_rcp(cd);
    t.beta = fminf(fmaxf(fast_atan_small(0.45f * t.tan_d), -0.65f), 0.65f);
    t.acc = fminf(fmaxf(2.8f * t.fx - 6.5f * t.fb, neg_brake_lim), 3.0f);
    return t;
}

__global__ __launch_bounds__(64) void degraded_bicycle_rollout_kernel(
    const float* __restrict__ x0,        // [512,12]
    const float* __restrict__ controls,  // [512,64,80,3]
    const float* __restrict__ deg,       // [512,5]
    float* __restrict__ out)             // [512,64,81,12]
{
    const int tid = blockIdx.x * 64 + threadIdx.x;   // rollout id = b*64 + l
    const int b = tid >> 6;

    const float* dg = deg + b * 5;
    const float steer_scale    = fmaxf(dg[0], 0.05f);
    const float brake_scale    = fmaxf(dg[1], 0.05f);
    const float throttle_scale = fmaxf(dg[2], 0.05f);
    const float friction       = fmaxf(dg[4], 0.1f);

    const float4* x0v = reinterpret_cast<const float4*>(x0 + b * 12);
    const float4 xi0 = x0v[0];
    const float4 xi1 = x0v[1];
    const float4 xi2 = x0v[2];

    float* o = out + (size_t)tid * 972;   // 81*12 floats per rollout
    {
        float4* ov = reinterpret_cast<float4*>(o);
        ov[0] = xi0; ov[1] = xi1; ov[2] = xi2;   // h = 0 row
    }

    float px  = xi0.x;
    float py  = xi0.y;
    float psi = xi0.z;
    float vx  = xi0.w;
    float vy  = xi1.x;

    const float4* uc = reinterpret_cast<const float4*>(controls + (size_t)tid * 240);

    const float neg_brake_lim = -7.5f * friction;
    const float yaw_num = friction * 9.81f;
    const float inv_wheelbase = 1.0f / 2.8f;

    // prefetch group 0 controls
    float4 c0 = uc[0];
    float4 c1 = uc[1];
    float4 c2 = uc[2];

    for (int g = 0; g < N_H / 4; ++g) {
        // prefetch group g+1 BEFORE this group's stores are issued, so the
        // wait for them next iteration needs vmcnt(>=12), never a store drain.
        float4 n0, n1, n2;
        if (g < N_H / 4 - 1) {
            n0 = uc[(g + 1) * 3 + 0];
            n1 = uc[(g + 1) * 3 + 1];
            n2 = uc[(g + 1) * 3 + 2];
        }

        // state-independent transforms for all 4 steps (ILP ahead of chain)
        const Ctl tA = make_ctl(c0.x, c0.y, c0.z, steer_scale, brake_scale, throttle_scale, neg_brake_lim);
        const Ctl tB = make_ctl(c0.w, c1.x, c1.y, steer_scale, brake_scale, throttle_scale, neg_brake_lim);
        const Ctl tC = make_ctl(c1.z, c1.w, c2.x, steer_scale, brake_scale, throttle_scale, neg_brake_lim);
        const Ctl tD = make_ctl(c2.y, c2.z, c2.w, steer_scale, brake_scale, throttle_scale, neg_brake_lim);

#define ROLL_STEP(T, HIDX)                                                        \
        {                                                                         \
            const float speed  = __builtin_amdgcn_sqrtf(fmaf(vx, vx, fmaf(vy, vy, 1e-6f))); \
            const float speed2 = fmaxf(fmaf((T).acc, DT_F, speed), 0.0f);         \
            const float raw_yaw = speed2 * inv_wheelbase * (T).tan_d;             \
            const float yaw_lim = fmaxf(yaw_num * fast_rcp(fmaxf(speed2, 2.0f)), 0.15f); \
            const float yaw_rate = fminf(fmaxf(raw_yaw, -1.0f), 1.0f) * yaw_lim;  \
            const float psi2 = fmaf(yaw_rate, DT_F, psi);                         \
            float s_, c_;                                                         \
            __sincosf(psi2 + (T).beta, &s_, &c_);                                 \
            const float vx2 = speed2 * c_;                                        \
            const float vy2 = speed2 * s_;                                        \
            const float px2 = fmaf(vx2, DT_F, px);                                \
            const float py2 = fmaf(vy2, DT_F, py);                                \
            const float ax = (vx2 - vx) * 10.0f;                                  \
            const float ay = (vy2 - vy) * 10.0f;                                  \
            float4* wp = reinterpret_cast<float4*>(o + (size_t)((HIDX) + 1) * 12);\
            wp[0] = make_float4(px2, py2, psi2, vx2);                             \
            wp[1] = make_float4(vy2, yaw_rate, ax, ay);                           \
            wp[2] = make_float4((T).beta, (T).delta, (T).fb, (T).fx);             \
            px = px2; py = py2; psi = psi2; vx = vx2; vy = vy2;                   \
        }

        const int h0 = g * 4;
        ROLL_STEP(tA, h0 + 0)
        ROLL_STEP(tB, h0 + 1)
        ROLL_STEP(tC, h0 + 2)
        ROLL_STEP(tD, h0 + 3)
#undef ROLL_STEP

        c0 = n0; c1 = n1; c2 = n2;
    }
}

extern "C" void kernel_launch(void* const* d_in, const int* in_sizes, int n_in,
                              void* d_out, int out_size, void* d_ws, size_t ws_size,
                              hipStream_t stream) {
    (void)in_sizes; (void)n_in; (void)d_ws; (void)ws_size; (void)out_size;
    const float* x0       = (const float*)d_in[0];
    const float* controls = (const float*)d_in[1];
    const float* deg      = (const float*)d_in[2];
    float* out            = (float*)d_out;

    const int total = N_B * N_L;            // 32768 rollouts
    dim3 grid(total / 64), block(64);       // 512 blocks x 1 wave each
    hipLaunchKernelGGL(degraded_bicycle_rollout_kernel, grid, block, 0, stream,
                       x0, controls, deg, out);
}

// Round 4
// 39.822 us; speedup vs baseline: 1.7569x; 1.6570x over previous
//
#include <hip/hip_runtime.h>
#include <math.h>

// DegradedBicycleRollout: b=512, l=64, h=80, state=12.
// R4: stores were the limiter (64-way scattered 16B stores, 7.9M transactions).
// Stage output in LDS per 20-step chunk, flush lane-coalesced.
// Block = 1 wave = one b (64 l-rollouts). No __syncthreads (single wave).
// LDS [64 l][61 float4]: pitch 61 (odd, ≡5 mod 8) -> compute-phase b128 writes
// hit distinct bank-quads per 8-lane group; flush reads are consecutive-q.

#define N_B 512
#define N_L 64
#define N_H 80
#define DT_F 0.1f
#define PITCH_F4 61      // float4s per l-row in LDS (60 used + 1 pad)
#define STEPS_PER_CHUNK 20

__device__ __forceinline__ float fast_rcp(float x) { return __builtin_amdgcn_rcpf(x); }

__device__ __forceinline__ float fast_tanh(float x) {
    const float e2 = __expf(2.0f * x);
    return (e2 - 1.0f) * fast_rcp(e2 + 1.0f);
}

__device__ __forceinline__ float fast_sigmoid(float x) {
    return fast_rcp(1.0f + __expf(-x));
}

__device__ __forceinline__ float fast_atan_small(float z) {
    // |z| <= 0.42 here; odd Taylor through z^9, max err ~1e-5.
    const float z2 = z * z;
    float p = 1.0f / 9.0f;
    p = fmaf(p, z2, -1.0f / 7.0f);
    p = fmaf(p, z2, 1.0f / 5.0f);
    p = fmaf(p, z2, -1.0f / 3.0f);
    p = fmaf(p, z2, 1.0f);
    return z * p;
}

struct Ctl { float delta, fb, fx, tan_d, beta, acc; };

__device__ __forceinline__ Ctl make_ctl(float u0, float u1, float u2,
                                        float steer_scale, float brake_scale,
                                        float throttle_scale, float neg_brake_lim) {
    Ctl t;
    t.delta = steer_scale * fast_tanh(u0);
    t.fb = brake_scale    * fast_sigmoid(u1);
    t.fx = throttle_scale * fast_sigmoid(u2);
    const float dc = fminf(fmaxf(t.delta, -0.75f), 0.75f);
    float sd, cd;
    __sincosf(dc, &sd, &cd);
    t.tan_d = sd * fast_rcp(cd);
    t.beta = fminf(fmaxf(fast_atan_small(0.45f * t.tan_d), -0.65f), 0.65f);
    t.acc = fminf(fmaxf(2.8f * t.fx - 6.5f * t.fb, neg_brake_lim), 3.0f);
    return t;
}

__global__ __launch_bounds__(64) void degraded_bicycle_rollout_kernel(
    const float* __restrict__ x0,        // [512,12]
    const float* __restrict__ controls,  // [512,64,80,3]
    const float* __restrict__ deg,       // [512,5]
    float* __restrict__ out)             // [512,64,81,12]
{
    __shared__ float4 lds4[N_L * PITCH_F4];   // 62.5 KB -> 2 blocks/CU

    const int lane = threadIdx.x;
    const int b = blockIdx.x;                 // one b per block
    const int tid = b * 64 + lane;            // rollout id

    const float* dg = deg + b * 5;            // wave-uniform -> scalar loads
    const float steer_scale    = fmaxf(dg[0], 0.05f);
    const float brake_scale    = fmaxf(dg[1], 0.05f);
    const float throttle_scale = fmaxf(dg[2], 0.05f);
    const float friction       = fmaxf(dg[4], 0.1f);

    const float4* x0v = reinterpret_cast<const float4*>(x0 + b * 12);
    const float4 xi0 = x0v[0];
    const float4 xi1 = x0v[1];
    const float4 xi2 = x0v[2];

    // h = 0 row: direct (scattered, but only 3 store instrs total)
    {
        float4* ov = reinterpret_cast<float4*>(out + (size_t)tid * 972);
        ov[0] = xi0; ov[1] = xi1; ov[2] = xi2;
    }

    float px  = xi0.x;
    float py  = xi0.y;
    float psi = xi0.z;
    float vx  = xi0.w;
    float vy  = xi1.x;

    const float4* uc = reinterpret_cast<const float4*>(controls + (size_t)tid * 240);

    const float neg_brake_lim = -7.5f * friction;
    const float yaw_num = friction * 9.81f;
    const float inv_wheelbase = 1.0f / 2.8f;

    float4* lrow = &lds4[lane * PITCH_F4];

    // prefetch group 0 controls (3 float4 = 4 steps)
    float4 c0 = uc[0];
    float4 c1 = uc[1];
    float4 c2 = uc[2];

    for (int c = 0; c < 4; ++c) {             // 4 chunks x 20 steps
        #pragma unroll
        for (int gg = 0; gg < 5; ++gg) {      // 5 groups of 4 steps
            const int g = c * 5 + gg;
            float4 n0 = c0, n1 = c1, n2 = c2;
            if (g < 19) {
                n0 = uc[(g + 1) * 3 + 0];
                n1 = uc[(g + 1) * 3 + 1];
                n2 = uc[(g + 1) * 3 + 2];
            }

            const Ctl tA = make_ctl(c0.x, c0.y, c0.z, steer_scale, brake_scale, throttle_scale, neg_brake_lim);
            const Ctl tB = make_ctl(c0.w, c1.x, c1.y, steer_scale, brake_scale, throttle_scale, neg_brake_lim);
            const Ctl tC = make_ctl(c1.z, c1.w, c2.x, steer_scale, brake_scale, throttle_scale, neg_brake_lim);
            const Ctl tD = make_ctl(c2.y, c2.z, c2.w, steer_scale, brake_scale, throttle_scale, neg_brake_lim);

#define ROLL_STEP(T, RR)                                                          \
            {                                                                     \
                const float speed  = __builtin_amdgcn_sqrtf(fmaf(vx, vx, fmaf(vy, vy, 1e-6f))); \
                const float speed2 = fmaxf(fmaf((T).acc, DT_F, speed), 0.0f);     \
                const float raw_yaw = speed2 * inv_wheelbase * (T).tan_d;         \
                const float yaw_lim = fmaxf(yaw_num * fast_rcp(fmaxf(speed2, 2.0f)), 0.15f); \
                const float yaw_rate = fminf(fmaxf(raw_yaw, -1.0f), 1.0f) * yaw_lim; \
                const float psi2 = fmaf(yaw_rate, DT_F, psi);                     \
                float s_, c_;                                                     \
                __sincosf(psi2 + (T).beta, &s_, &c_);                             \
                const float vx2 = speed2 * c_;                                    \
                const float vy2 = speed2 * s_;                                    \
                const float px2 = fmaf(vx2, DT_F, px);                            \
                const float py2 = fmaf(vy2, DT_F, py);                            \
                const float ax = (vx2 - vx) * 10.0f;                              \
                const float ay = (vy2 - vy) * 10.0f;                              \
                lrow[(RR) * 3 + 0] = make_float4(px2, py2, psi2, vx2);            \
                lrow[(RR) * 3 + 1] = make_float4(vy2, yaw_rate, ax, ay);          \
                lrow[(RR) * 3 + 2] = make_float4((T).beta, (T).delta, (T).fb, (T).fx); \
                px = px2; py = py2; psi = psi2; vx = vx2; vy = vy2;               \
            }

            ROLL_STEP(tA, gg * 4 + 0)
            ROLL_STEP(tB, gg * 4 + 1)
            ROLL_STEP(tC, gg * 4 + 2)
            ROLL_STEP(tD, gg * 4 + 3)
#undef ROLL_STEP

            c0 = n0; c1 = n1; c2 = n2;
        }

        // Flush chunk c: 20 steps x 64 l = 3840 float4, lane-coalesced.
        // flat = i*64+lane; l = flat/60, q = flat%60.
        // out float offset: (b*64+l)*972 + 12 + c*240 + 4q  (all mult of 4)
        const size_t out_chunk = (size_t)b * 62208 + 12 + c * 240; // b*64*972
        #pragma unroll 10
        for (int i = 0; i < 60; ++i) {
            const int flat = i * 64 + lane;
            const int l = flat / 60;
            const int q = flat - l * 60;
            const float4 v = lds4[l * PITCH_F4 + q];
            *reinterpret_cast<float4*>(out + out_chunk + (size_t)l * 972 + q * 4) = v;
        }
    }
}

extern "C" void kernel_launch(void* const* d_in, const int* in_sizes, int n_in,
                              void* d_out, int out_size, void* d_ws, size_t ws_size,
                              hipStream_t stream) {
    (void)in_sizes; (void)n_in; (void)d_ws; (void)ws_size; (void)out_size;
    const float* x0       = (const float*)d_in[0];
    const float* controls = (const float*)d_in[1];
    const float* deg      = (const float*)d_in[2];
    float* out            = (float*)d_out;

    dim3 grid(N_B), block(64);                // 512 blocks x 1 wave
    hipLaunchKernelGGL(degraded_bicycle_rollout_kernel, grid, block, 0, stream,
                       x0, controls, deg, out);
}

// Round 5
// 35.427 us; speedup vs baseline: 1.9749x; 1.1241x over previous
//
#include <hip/hip_runtime.h>
#include <math.h>

// DegradedBicycleRollout: b=512, l=64, h=80, state=12.
// R5: double-buffered LDS staging; flush of chunk c-1 interleaved into the
// compute of chunk c so store traffic issues into the serial chain's stall
// slots (2 waves/CU -> within-wave overlap is all we have).
// Chunk = 8 steps. LDS = 2 x 64 x 25 float4 = 51.2 KB -> 2 blocks/CU (102KB).
// Pitch 25 f4 (=> 25 mod 8 = 1) -> conflict-free ds_write_b128.

#define N_B 512
#define N_L 64
#define N_H 80
#define DT_F 0.1f
#define PITCH_F4 25       // 24 used + 1 pad
#define SPC 8             // steps per chunk
#define NCH 10            // chunks

__device__ __forceinline__ float fast_rcp(float x) { return __builtin_amdgcn_rcpf(x); }

__device__ __forceinline__ float fast_tanh(float x) {
    const float e2 = __expf(2.0f * x);
    return (e2 - 1.0f) * fast_rcp(e2 + 1.0f);
}

__device__ __forceinline__ float fast_sigmoid(float x) {
    return fast_rcp(1.0f + __expf(-x));
}

__device__ __forceinline__ float fast_atan_small(float z) {
    // |z| <= 0.42 here; odd Taylor through z^9, max err ~1e-5.
    const float z2 = z * z;
    float p = 1.0f / 9.0f;
    p = fmaf(p, z2, -1.0f / 7.0f);
    p = fmaf(p, z2, 1.0f / 5.0f);
    p = fmaf(p, z2, -1.0f / 3.0f);
    p = fmaf(p, z2, 1.0f);
    return z * p;
}

struct Ctl { float delta, fb, fx, tan_d, beta, acc; };

__device__ __forceinline__ Ctl make_ctl(float u0, float u1, float u2,
                                        float steer_scale, float brake_scale,
                                        float throttle_scale, float neg_brake_lim) {
    Ctl t;
    t.delta = steer_scale * fast_tanh(u0);
    t.fb = brake_scale    * fast_sigmoid(u1);
    t.fx = throttle_scale * fast_sigmoid(u2);
    const float dc = fminf(fmaxf(t.delta, -0.75f), 0.75f);
    float sd, cd;
    __sincosf(dc, &sd, &cd);
    t.tan_d = sd * fast_rcp(cd);
    t.beta = fminf(fmaxf(fast_atan_small(0.45f * t.tan_d), -0.65f), 0.65f);
    t.acc = fminf(fmaxf(2.8f * t.fx - 6.5f * t.fb, neg_brake_lim), 3.0f);
    return t;
}

__global__ __launch_bounds__(64) void degraded_bicycle_rollout_kernel(
    const float* __restrict__ x0,        // [512,12]
    const float* __restrict__ controls,  // [512,64,80,3]
    const float* __restrict__ deg,       // [512,5]
    float* __restrict__ out)             // [512,64,81,12]
{
    __shared__ float4 lds4[2][N_L * PITCH_F4];   // 2 x 25.6 KB

    const int lane = threadIdx.x;
    const int b = blockIdx.x;                 // one b per block (1 wave)
    const int tid = b * 64 + lane;

    const float* dg = deg + b * 5;            // wave-uniform
    const float steer_scale    = fmaxf(dg[0], 0.05f);
    const float brake_scale    = fmaxf(dg[1], 0.05f);
    const float throttle_scale = fmaxf(dg[2], 0.05f);
    const float friction       = fmaxf(dg[4], 0.1f);

    const float4* x0v = reinterpret_cast<const float4*>(x0 + b * 12);
    const float4 xi0 = x0v[0];
    const float4 xi1 = x0v[1];
    const float4 xi2 = x0v[2];

    // h = 0 row: direct scattered store (3 instrs total, negligible)
    {
        float4* ov = reinterpret_cast<float4*>(out + (size_t)tid * 972);
        ov[0] = xi0; ov[1] = xi1; ov[2] = xi2;
    }

    float px  = xi0.x;
    float py  = xi0.y;
    float psi = xi0.z;
    float vx  = xi0.w;
    float vy  = xi1.x;

    const float4* uc = reinterpret_cast<const float4*>(controls + (size_t)tid * 240);

    const float neg_brake_lim = -7.5f * friction;
    const float yaw_num = friction * 9.81f;
    const float inv_wheelbase = 1.0f / 2.8f;

    const size_t out_b = (size_t)b * 62208 + 12;   // b*64*972 + skip h=0 row

    // flush slice: f4 index i in [i0,i1) of chunk fc from buffer fbuf
#define FLUSH_SLICE(FBUF, FC, I0, I1)                                             \
    {                                                                             \
        const size_t obase = out_b + (size_t)(FC) * (SPC * 12);                   \
        _Pragma("unroll")                                                         \
        for (int i = (I0); i < (I1); ++i) {                                       \
            const unsigned flat = i * 64 + lane;                                  \
            const unsigned l = flat / 24u;                                        \
            const unsigned q = flat - l * 24u;                                    \
            const float4 v = lds4[FBUF][l * PITCH_F4 + q];                        \
            *reinterpret_cast<float4*>(out + obase + (size_t)l * 972 + q * 4) = v;\
        }                                                                         \
    }

    // prefetch group 0 controls (3 float4 = 4 steps)
    float4 c0 = uc[0];
    float4 c1 = uc[1];
    float4 c2 = uc[2];

    for (int c = 0; c < NCH; ++c) {           // 10 chunks x 8 steps
        const int cur = c & 1;
        float4* lrow = &lds4[cur][lane * PITCH_F4];

        #pragma unroll
        for (int gg = 0; gg < 2; ++gg) {      // 2 groups of 4 steps
            const int g = c * 2 + gg;
            float4 n0 = c0, n1 = c1, n2 = c2;
            if (g < 19) {
                n0 = uc[(g + 1) * 3 + 0];
                n1 = uc[(g + 1) * 3 + 1];
                n2 = uc[(g + 1) * 3 + 2];
            }

            const Ctl tA = make_ctl(c0.x, c0.y, c0.z, steer_scale, brake_scale, throttle_scale, neg_brake_lim);
            const Ctl tB = make_ctl(c0.w, c1.x, c1.y, steer_scale, brake_scale, throttle_scale, neg_brake_lim);
            const Ctl tC = make_ctl(c1.z, c1.w, c2.x, steer_scale, brake_scale, throttle_scale, neg_brake_lim);
            const Ctl tD = make_ctl(c2.y, c2.z, c2.w, steer_scale, brake_scale, throttle_scale, neg_brake_lim);

#define ROLL_STEP(T, RR)                                                          \
            {                                                                     \
                const float speed  = __builtin_amdgcn_sqrtf(fmaf(vx, vx, fmaf(vy, vy, 1e-6f))); \
                const float speed2 = fmaxf(fmaf((T).acc, DT_F, speed), 0.0f);     \
                const float raw_yaw = speed2 * inv_wheelbase * (T).tan_d;         \
                const float yaw_lim = fmaxf(yaw_num * fast_rcp(fmaxf(speed2, 2.0f)), 0.15f); \
                const float yaw_rate = fminf(fmaxf(raw_yaw, -1.0f), 1.0f) * yaw_lim; \
                const float psi2 = fmaf(yaw_rate, DT_F, psi);                     \
                float s_, c_;                                                     \
                __sincosf(psi2 + (T).beta, &s_, &c_);                             \
                const float vx2 = speed2 * c_;                                    \
                const float vy2 = speed2 * s_;                                    \
                const float px2 = fmaf(vx2, DT_F, px);                            \
                const float py2 = fmaf(vy2, DT_F, py);                            \
                const float ax = (vx2 - vx) * 10.0f;                              \
                const float ay = (vy2 - vy) * 10.0f;                              \
                lrow[(RR) * 3 + 0] = make_float4(px2, py2, psi2, vx2);            \
                lrow[(RR) * 3 + 1] = make_float4(vy2, yaw_rate, ax, ay);          \
                lrow[(RR) * 3 + 2] = make_float4((T).beta, (T).delta, (T).fb, (T).fx); \
                px = px2; py = py2; psi = psi2; vx = vx2; vy = vy2;               \
            }

            ROLL_STEP(tA, gg * 4 + 0)
            ROLL_STEP(tB, gg * 4 + 1)
            ROLL_STEP(tC, gg * 4 + 2)
            ROLL_STEP(tD, gg * 4 + 3)
#undef ROLL_STEP

            c0 = n0; c1 = n1; c2 = n2;

            // interleave: flush half of chunk c-1 from the other buffer
            if (c > 0) {
                if (gg == 0) FLUSH_SLICE(cur ^ 1, c - 1, 0, 12)
                else         FLUSH_SLICE(cur ^ 1, c - 1, 12, 24)
            }
        }
    }

    // epilogue: flush last chunk (NCH-1) from buf[(NCH-1)&1]
    FLUSH_SLICE((NCH - 1) & 1, NCH - 1, 0, 24)
#undef FLUSH_SLICE
}

extern "C" void kernel_launch(void* const* d_in, const int* in_sizes, int n_in,
                              void* d_out, int out_size, void* d_ws, size_t ws_size,
                              hipStream_t stream) {
    (void)in_sizes; (void)n_in; (void)d_ws; (void)ws_size; (void)out_size;
    const float* x0       = (const float*)d_in[0];
    const float* controls = (const float*)d_in[1];
    const float* deg      = (const float*)d_in[2];
    float* out            = (float*)d_out;

    dim3 grid(N_B), block(64);                // 512 blocks x 1 wave
    hipLaunchKernelGGL(degraded_bicycle_rollout_kernel, grid, block, 0, stream,
                       x0, controls, deg, out);
}

// Round 6
// 35.250 us; speedup vs baseline: 1.9848x; 1.0050x over previous
//
#include <hip/hip_runtime.h>
#include <math.h>

// DegradedBicycleRollout: b=512, l=64, h=80, state=12.
// R6: producer-consumer wave specialization. Block = 2 waves per b:
//   wave 0 (compute): serial rollout, writes 8-step chunks to LDS dbuf.
//   wave 1 (writer):  flushes chunk c-1 coalesced while wave 0 computes c.
// One __syncthreads per chunk. Writer keeps the store queue full continuously
// (R5 post-mortem: single wave alternating compute/flush left stores idle ->
// 4.3 TB/s effective vs ~7 TB/s fill-kernel rate).
// LDS = 2 x 64 x 25 f4 = 51.2 KB -> 2 blocks/CU (4 waves/CU, 1/SIMD).

#define N_B 512
#define N_L 64
#define N_H 80
#define DT_F 0.1f
#define PITCH_F4 25       // 24 used + 1 pad (lane stride 100 dwords -> 2-way max, free)
#define SPC 8             // steps per chunk
#define NCH 10            // chunks

__device__ __forceinline__ float fast_rcp(float x) { return __builtin_amdgcn_rcpf(x); }

__device__ __forceinline__ float fast_tanh(float x) {
    const float e2 = __expf(2.0f * x);
    return (e2 - 1.0f) * fast_rcp(e2 + 1.0f);
}

__device__ __forceinline__ float fast_sigmoid(float x) {
    return fast_rcp(1.0f + __expf(-x));
}

__device__ __forceinline__ float fast_atan_small(float z) {
    // |z| <= 0.42 here; odd Taylor through z^9, max err ~1e-5.
    const float z2 = z * z;
    float p = 1.0f / 9.0f;
    p = fmaf(p, z2, -1.0f / 7.0f);
    p = fmaf(p, z2, 1.0f / 5.0f);
    p = fmaf(p, z2, -1.0f / 3.0f);
    p = fmaf(p, z2, 1.0f);
    return z * p;
}

struct Ctl { float delta, fb, fx, tan_d, beta, acc; };

__device__ __forceinline__ Ctl make_ctl(float u0, float u1, float u2,
                                        float steer_scale, float brake_scale,
                                        float throttle_scale, float neg_brake_lim) {
    Ctl t;
    t.delta = steer_scale * fast_tanh(u0);
    t.fb = brake_scale    * fast_sigmoid(u1);
    t.fx = throttle_scale * fast_sigmoid(u2);
    const float dc = fminf(fmaxf(t.delta, -0.75f), 0.75f);
    float sd, cd;
    __sincosf(dc, &sd, &cd);
    t.tan_d = sd * fast_rcp(cd);
    t.beta = fminf(fmaxf(fast_atan_small(0.45f * t.tan_d), -0.65f), 0.65f);
    t.acc = fminf(fmaxf(2.8f * t.fx - 6.5f * t.fb, neg_brake_lim), 3.0f);
    return t;
}

__global__ __launch_bounds__(128) void degraded_bicycle_rollout_kernel(
    const float* __restrict__ x0,        // [512,12]
    const float* __restrict__ controls,  // [512,64,80,3]
    const float* __restrict__ deg,       // [512,5]
    float* __restrict__ out)             // [512,64,81,12]
{
    __shared__ float4 lds4[2][N_L * PITCH_F4];   // 2 x 25.6 KB

    const int lane = threadIdx.x & 63;
    const int wave = threadIdx.x >> 6;        // 0 = compute, 1 = writer
    const int b = blockIdx.x;                 // one b per block

    const size_t out_b = (size_t)b * 62208;   // b*64*972 floats

    // ---- writer-side flush helper: f4 index i in [I0,I1) of chunk FC ----
#define FLUSH_SLICE(FBUF, FC, I0, I1)                                             \
    {                                                                             \
        const size_t obase = out_b + 12 + (size_t)(FC) * (SPC * 12);              \
        _Pragma("unroll")                                                         \
        for (int i = (I0); i < (I1); ++i) {                                       \
            const unsigned flat = i * 64 + lane;                                  \
            const unsigned l = flat / 24u;                                        \
            const unsigned q = flat - l * 24u;                                    \
            const float4 v = lds4[FBUF][l * PITCH_F4 + q];                        \
            *reinterpret_cast<float4*>(out + obase + (size_t)l * 972 + q * 4) = v;\
        }                                                                         \
    }

    if (wave == 0) {
        // ================= compute persona =================
        const float* dg = deg + b * 5;
        const float steer_scale    = fmaxf(dg[0], 0.05f);
        const float brake_scale    = fmaxf(dg[1], 0.05f);
        const float throttle_scale = fmaxf(dg[2], 0.05f);
        const float friction       = fmaxf(dg[4], 0.1f);

        const float4* x0v = reinterpret_cast<const float4*>(x0 + b * 12);
        const float4 xi0 = x0v[0];
        const float4 xi1 = x0v[1];

        float px  = xi0.x;
        float py  = xi0.y;
        float psi = xi0.z;
        float vx  = xi0.w;
        float vy  = xi1.x;

        const int tid = b * 64 + lane;
        const float4* uc = reinterpret_cast<const float4*>(controls + (size_t)tid * 240);

        const float neg_brake_lim = -7.5f * friction;
        const float yaw_num = friction * 9.81f;
        const float inv_wheelbase = 1.0f / 2.8f;

        // prefetch group 0 controls (3 float4 = 4 steps)
        float4 c0 = uc[0];
        float4 c1 = uc[1];
        float4 c2 = uc[2];

        for (int c = 0; c < NCH; ++c) {
            float4* lrow = &lds4[c & 1][lane * PITCH_F4];

            #pragma unroll
            for (int gg = 0; gg < 2; ++gg) {  // 2 groups of 4 steps
                const int g = c * 2 + gg;
                float4 n0 = c0, n1 = c1, n2 = c2;
                if (g < 19) {
                    n0 = uc[(g + 1) * 3 + 0];
                    n1 = uc[(g + 1) * 3 + 1];
                    n2 = uc[(g + 1) * 3 + 2];
                }

                const Ctl tA = make_ctl(c0.x, c0.y, c0.z, steer_scale, brake_scale, throttle_scale, neg_brake_lim);
                const Ctl tB = make_ctl(c0.w, c1.x, c1.y, steer_scale, brake_scale, throttle_scale, neg_brake_lim);
                const Ctl tC = make_ctl(c1.z, c1.w, c2.x, steer_scale, brake_scale, throttle_scale, neg_brake_lim);
                const Ctl tD = make_ctl(c2.y, c2.z, c2.w, steer_scale, brake_scale, throttle_scale, neg_brake_lim);

#define ROLL_STEP(T, RR)                                                          \
                {                                                                 \
                    const float speed  = __builtin_amdgcn_sqrtf(fmaf(vx, vx, fmaf(vy, vy, 1e-6f))); \
                    const float speed2 = fmaxf(fmaf((T).acc, DT_F, speed), 0.0f); \
                    const float raw_yaw = speed2 * inv_wheelbase * (T).tan_d;     \
                    const float yaw_lim = fmaxf(yaw_num * fast_rcp(fmaxf(speed2, 2.0f)), 0.15f); \
                    const float yaw_rate = fminf(fmaxf(raw_yaw, -1.0f), 1.0f) * yaw_lim; \
                    const float psi2 = fmaf(yaw_rate, DT_F, psi);                 \
                    float s_, c_;                                                 \
                    __sincosf(psi2 + (T).beta, &s_, &c_);                         \
                    const float vx2 = speed2 * c_;                                \
                    const float vy2 = speed2 * s_;                                \
                    const float px2 = fmaf(vx2, DT_F, px);                        \
                    const float py2 = fmaf(vy2, DT_F, py);                        \
                    const float ax = (vx2 - vx) * 10.0f;                          \
                    const float ay = (vy2 - vy) * 10.0f;                          \
                    lrow[(RR) * 3 + 0] = make_float4(px2, py2, psi2, vx2);        \
                    lrow[(RR) * 3 + 1] = make_float4(vy2, yaw_rate, ax, ay);      \
                    lrow[(RR) * 3 + 2] = make_float4((T).beta, (T).delta, (T).fb, (T).fx); \
                    px = px2; py = py2; psi = psi2; vx = vx2; vy = vy2;           \
                }

                ROLL_STEP(tA, gg * 4 + 0)
                ROLL_STEP(tB, gg * 4 + 1)
                ROLL_STEP(tC, gg * 4 + 2)
                ROLL_STEP(tD, gg * 4 + 3)
#undef ROLL_STEP

                c0 = n0; c1 = n1; c2 = n2;
            }
            __syncthreads();   // chunk c ready; writer done with buf[c&1] from c-2
        }
    } else {
        // ================= writer persona =================
        // During c==0 (nothing staged yet): write the h=0 rows.
        // out[(b*64+l)*972 + 0..11] = x0[b][0..11] for all 64 l.
        {
            const float4* x0v = reinterpret_cast<const float4*>(x0 + b * 12);
            const float4 xq0 = x0v[0];
            const float4 xq1 = x0v[1];
            const float4 xq2 = x0v[2];
            // 64 l x 3 f4 = 192 f4 = 3 wave-instrs: flat = i*64+lane, l=flat/3, q=flat%3
            #pragma unroll
            for (int i = 0; i < 3; ++i) {
                const unsigned flat = i * 64 + lane;
                const unsigned l = flat / 3u;
                const unsigned q = flat - l * 3u;
                const float4 v = (q == 0) ? xq0 : (q == 1) ? xq1 : xq2;
                *reinterpret_cast<float4*>(out + out_b + (size_t)l * 972 + q * 4) = v;
            }
        }
        for (int c = 0; c < NCH; ++c) {
            if (c > 0) FLUSH_SLICE((c - 1) & 1, c - 1, 0, 24)
            __syncthreads();   // matches compute wave's barrier
        }
        // epilogue: last chunk
        FLUSH_SLICE((NCH - 1) & 1, NCH - 1, 0, 24)
    }
#undef FLUSH_SLICE
}

extern "C" void kernel_launch(void* const* d_in, const int* in_sizes, int n_in,
                              void* d_out, int out_size, void* d_ws, size_t ws_size,
                              hipStream_t stream) {
    (void)in_sizes; (void)n_in; (void)d_ws; (void)ws_size; (void)out_size;
    const float* x0       = (const float*)d_in[0];
    const float* controls = (const float*)d_in[1];
    const float* deg      = (const float*)d_in[2];
    float* out            = (float*)d_out;

    dim3 grid(N_B), block(128);               // 512 blocks x 2 waves (compute+writer)
    hipLaunchKernelGGL(degraded_bicycle_rollout_kernel, grid, block, 0, stream,
                       x0, controls, deg, out);
}

// Round 7
// 35.180 us; speedup vs baseline: 1.9887x; 1.0020x over previous
//
#include <hip/hip_runtime.h>
#include <math.h>

// DegradedBicycleRollout: b=512, l=64, h=80, state=12.
// R7: R6 structure (compute wave + writer wave per b, LDS dbuf, 8-step chunks)
// with __sincosf replaced by raw v_sin_f32/v_cos_f32 (__builtin_amdgcn_sinf/cosf,
// explicit 1/(2pi) scaling). R6 post-mortem: compute wave alone is ~35us
// (~425 cyc/step); suspect __sincosf lowers to precise ocml sincos (2 calls/step).
// HW v_sin computes sin(2pi*x), valid |x|<=256 rev; our angles <=~7 rev.

#define N_B 512
#define N_L 64
#define N_H 80
#define DT_F 0.1f
#define PITCH_F4 25       // 24 used + 1 pad
#define SPC 8             // steps per chunk
#define NCH 10            // chunks
#define INV2PI 0.15915494309189535f

__device__ __forceinline__ float fast_rcp(float x) { return __builtin_amdgcn_rcpf(x); }

__device__ __forceinline__ float fast_tanh(float x) {
    const float e2 = __expf(2.0f * x);
    return (e2 - 1.0f) * fast_rcp(e2 + 1.0f);
}

__device__ __forceinline__ float fast_sigmoid(float x) {
    return fast_rcp(1.0f + __expf(-x));
}

__device__ __forceinline__ float fast_atan_small(float z) {
    // |z| <= 0.42 here; odd Taylor through z^9, max err ~1e-5.
    const float z2 = z * z;
    float p = 1.0f / 9.0f;
    p = fmaf(p, z2, -1.0f / 7.0f);
    p = fmaf(p, z2, 1.0f / 5.0f);
    p = fmaf(p, z2, -1.0f / 3.0f);
    p = fmaf(p, z2, 1.0f);
    return z * p;
}

struct Ctl { float delta, fb, fx, tan_d, beta, acc; };

__device__ __forceinline__ Ctl make_ctl(float u0, float u1, float u2,
                                        float steer_scale, float brake_scale,
                                        float throttle_scale, float neg_brake_lim) {
    Ctl t;
    t.delta = steer_scale * fast_tanh(u0);
    t.fb = brake_scale    * fast_sigmoid(u1);
    t.fx = throttle_scale * fast_sigmoid(u2);
    const float dc = fminf(fmaxf(t.delta, -0.75f), 0.75f);
    const float dr = dc * INV2PI;                  // revolutions
    const float sd = __builtin_amdgcn_sinf(dr);    // v_sin_f32
    const float cd = __builtin_amdgcn_cosf(dr);    // v_cos_f32
    t.tan_d = sd * fast_rcp(cd);
    t.beta = fminf(fmaxf(fast_atan_small(0.45f * t.tan_d), -0.65f), 0.65f);
    t.acc = fminf(fmaxf(2.8f * t.fx - 6.5f * t.fb, neg_brake_lim), 3.0f);
    return t;
}

__global__ __launch_bounds__(128) void degraded_bicycle_rollout_kernel(
    const float* __restrict__ x0,        // [512,12]
    const float* __restrict__ controls,  // [512,64,80,3]
    const float* __restrict__ deg,       // [512,5]
    float* __restrict__ out)             // [512,64,81,12]
{
    __shared__ float4 lds4[2][N_L * PITCH_F4];   // 2 x 25.6 KB

    const int lane = threadIdx.x & 63;
    const int wave = threadIdx.x >> 6;        // 0 = compute, 1 = writer
    const int b = blockIdx.x;                 // one b per block

    const size_t out_b = (size_t)b * 62208;   // b*64*972 floats

#define FLUSH_SLICE(FBUF, FC, I0, I1)                                             \
    {                                                                             \
        const size_t obase = out_b + 12 + (size_t)(FC) * (SPC * 12);              \
        _Pragma("unroll")                                                         \
        for (int i = (I0); i < (I1); ++i) {                                       \
            const unsigned flat = i * 64 + lane;                                  \
            const unsigned l = flat / 24u;                                        \
            const unsigned q = flat - l * 24u;                                    \
            const float4 v = lds4[FBUF][l * PITCH_F4 + q];                        \
            *reinterpret_cast<float4*>(out + obase + (size_t)l * 972 + q * 4) = v;\
        }                                                                         \
    }

    if (wave == 0) {
        // ================= compute persona =================
        const float* dg = deg + b * 5;
        const float steer_scale    = fmaxf(dg[0], 0.05f);
        const float brake_scale    = fmaxf(dg[1], 0.05f);
        const float throttle_scale = fmaxf(dg[2], 0.05f);
        const float friction       = fmaxf(dg[4], 0.1f);

        const float4* x0v = reinterpret_cast<const float4*>(x0 + b * 12);
        const float4 xi0 = x0v[0];
        const float4 xi1 = x0v[1];

        float px  = xi0.x;
        float py  = xi0.y;
        float psi = xi0.z;
        float vx  = xi0.w;
        float vy  = xi1.x;

        const int tid = b * 64 + lane;
        const float4* uc = reinterpret_cast<const float4*>(controls + (size_t)tid * 240);

        const float neg_brake_lim = -7.5f * friction;
        const float yaw_num = friction * 9.81f;
        const float inv_wheelbase = 1.0f / 2.8f;

        // prefetch group 0 controls (3 float4 = 4 steps)
        float4 c0 = uc[0];
        float4 c1 = uc[1];
        float4 c2 = uc[2];

        for (int c = 0; c < NCH; ++c) {
            float4* lrow = &lds4[c & 1][lane * PITCH_F4];

            #pragma unroll
            for (int gg = 0; gg < 2; ++gg) {  // 2 groups of 4 steps
                const int g = c * 2 + gg;
                float4 n0 = c0, n1 = c1, n2 = c2;
                if (g < 19) {
                    n0 = uc[(g + 1) * 3 + 0];
                    n1 = uc[(g + 1) * 3 + 1];
                    n2 = uc[(g + 1) * 3 + 2];
                }

                const Ctl tA = make_ctl(c0.x, c0.y, c0.z, steer_scale, brake_scale, throttle_scale, neg_brake_lim);
                const Ctl tB = make_ctl(c0.w, c1.x, c1.y, steer_scale, brake_scale, throttle_scale, neg_brake_lim);
                const Ctl tC = make_ctl(c1.z, c1.w, c2.x, steer_scale, brake_scale, throttle_scale, neg_brake_lim);
                const Ctl tD = make_ctl(c2.y, c2.z, c2.w, steer_scale, brake_scale, throttle_scale, neg_brake_lim);

#define ROLL_STEP(T, RR)                                                          \
                {                                                                 \
                    const float speed  = __builtin_amdgcn_sqrtf(fmaf(vx, vx, fmaf(vy, vy, 1e-6f))); \
                    const float speed2 = fmaxf(fmaf((T).acc, DT_F, speed), 0.0f); \
                    const float raw_yaw = speed2 * inv_wheelbase * (T).tan_d;     \
                    const float yaw_lim = fmaxf(yaw_num * fast_rcp(fmaxf(speed2, 2.0f)), 0.15f); \
                    const float yaw_rate = fminf(fmaxf(raw_yaw, -1.0f), 1.0f) * yaw_lim; \
                    const float psi2 = fmaf(yaw_rate, DT_F, psi);                 \
                    const float ang = (psi2 + (T).beta) * INV2PI;                 \
                    const float s_ = __builtin_amdgcn_sinf(ang);                  \
                    const float c_ = __builtin_amdgcn_cosf(ang);                  \
                    const float vx2 = speed2 * c_;                                \
                    const float vy2 = speed2 * s_;                                \
                    const float px2 = fmaf(vx2, DT_F, px);                        \
                    const float py2 = fmaf(vy2, DT_F, py);                        \
                    const float ax = (vx2 - vx) * 10.0f;                          \
                    const float ay = (vy2 - vy) * 10.0f;                          \
                    lrow[(RR) * 3 + 0] = make_float4(px2, py2, psi2, vx2);        \
                    lrow[(RR) * 3 + 1] = make_float4(vy2, yaw_rate, ax, ay);      \
                    lrow[(RR) * 3 + 2] = make_float4((T).beta, (T).delta, (T).fb, (T).fx); \
                    px = px2; py = py2; psi = psi2; vx = vx2; vy = vy2;           \
                }

                ROLL_STEP(tA, gg * 4 + 0)
                ROLL_STEP(tB, gg * 4 + 1)
                ROLL_STEP(tC, gg * 4 + 2)
                ROLL_STEP(tD, gg * 4 + 3)
#undef ROLL_STEP

                c0 = n0; c1 = n1; c2 = n2;
            }
            __syncthreads();   // chunk c ready; writer done with buf[c&1] from c-2
        }
    } else {
        // ================= writer persona =================
        // During c==0: write the h=0 rows (64 l x 3 f4).
        {
            const float4* x0v = reinterpret_cast<const float4*>(x0 + b * 12);
            const float4 xq0 = x0v[0];
            const float4 xq1 = x0v[1];
            const float4 xq2 = x0v[2];
            #pragma unroll
            for (int i = 0; i < 3; ++i) {
                const unsigned flat = i * 64 + lane;
                const unsigned l = flat / 3u;
                const unsigned q = flat - l * 3u;
                const float4 v = (q == 0) ? xq0 : (q == 1) ? xq1 : xq2;
                *reinterpret_cast<float4*>(out + out_b + (size_t)l * 972 + q * 4) = v;
            }
        }
        for (int c = 0; c < NCH; ++c) {
            if (c > 0) FLUSH_SLICE((c - 1) & 1, c - 1, 0, 24)
            __syncthreads();
        }
        FLUSH_SLICE((NCH - 1) & 1, NCH - 1, 0, 24)
    }
#undef FLUSH_SLICE
}

extern "C" void kernel_launch(void* const* d_in, const int* in_sizes, int n_in,
                              void* d_out, int out_size, void* d_ws, size_t ws_size,
                              hipStream_t stream) {
    (void)in_sizes; (void)n_in; (void)d_ws; (void)ws_size; (void)out_size;
    const float* x0       = (const float*)d_in[0];
    const float* controls = (const float*)d_in[1];
    const float* deg      = (const float*)d_in[2];
    float* out            = (float*)d_out;

    dim3 grid(N_B), block(128);               // 512 blocks x 2 waves (compute+writer)
    hipLaunchKernelGGL(degraded_bicycle_rollout_kernel, grid, block, 0, stream,
                       x0, controls, deg, out);
}

// Round 8
// 34.187 us; speedup vs baseline: 2.0465x; 1.0290x over previous
//
#include <hip/hip_runtime.h>
#include <math.h>

// DegradedBicycleRollout: b=512, l=64, h=80, state=12.
// R8: writer wave = store flusher + CONTROL LOADER. Compute wave issues zero
// global loads; controls arrive via LDS (double-buffered, loaded coalesced by
// the writer one chunk ahead). R7 post-mortem: step chain ~1050cyc >> model;
// last un-attacked path was the 64-line-scatter control loads (L3 thrashed by
// the harness's 497MB poison fill between replays; FETCH_SIZE ~17MB/replay).
// LDS: out dbuf 2x64x25 f4 (51.2KB) + ctl dbuf 2x64x7 f4 (14.3KB) = 64KB
// -> 2 blocks/CU (4 waves/CU).

#define N_B 512
#define N_L 64
#define N_H 80
#define DT_F 0.1f
#define PITCH_F4 25       // out-buf pitch: 24 used + 1 pad
#define CPITCH 7          // ctl-buf pitch: 6 used + 1 pad (28 dwords -> distinct bank-quads)
#define SPC 8             // steps per chunk
#define NCH 10            // chunks
#define INV2PI 0.15915494309189535f

__device__ __forceinline__ float fast_rcp(float x) { return __builtin_amdgcn_rcpf(x); }

__device__ __forceinline__ float fast_tanh(float x) {
    const float e2 = __expf(2.0f * x);
    return (e2 - 1.0f) * fast_rcp(e2 + 1.0f);
}

__device__ __forceinline__ float fast_sigmoid(float x) {
    return fast_rcp(1.0f + __expf(-x));
}

__device__ __forceinline__ float fast_atan_small(float z) {
    // |z| <= 0.42 here; odd Taylor through z^9, max err ~1e-5.
    const float z2 = z * z;
    float p = 1.0f / 9.0f;
    p = fmaf(p, z2, -1.0f / 7.0f);
    p = fmaf(p, z2, 1.0f / 5.0f);
    p = fmaf(p, z2, -1.0f / 3.0f);
    p = fmaf(p, z2, 1.0f);
    return z * p;
}

struct Ctl { float delta, fb, fx, tan_d, beta, acc; };

__device__ __forceinline__ Ctl make_ctl(float u0, float u1, float u2,
                                        float steer_scale, float brake_scale,
                                        float throttle_scale, float neg_brake_lim) {
    Ctl t;
    t.delta = steer_scale * fast_tanh(u0);
    t.fb = brake_scale    * fast_sigmoid(u1);
    t.fx = throttle_scale * fast_sigmoid(u2);
    const float dc = fminf(fmaxf(t.delta, -0.75f), 0.75f);
    const float dr = dc * INV2PI;                  // revolutions
    const float sd = __builtin_amdgcn_sinf(dr);    // v_sin_f32
    const float cd = __builtin_amdgcn_cosf(dr);    // v_cos_f32
    t.tan_d = sd * fast_rcp(cd);
    t.beta = fminf(fmaxf(fast_atan_small(0.45f * t.tan_d), -0.65f), 0.65f);
    t.acc = fminf(fmaxf(2.8f * t.fx - 6.5f * t.fb, neg_brake_lim), 3.0f);
    return t;
}

__global__ __launch_bounds__(128) void degraded_bicycle_rollout_kernel(
    const float* __restrict__ x0,        // [512,12]
    const float* __restrict__ controls,  // [512,64,80,3]
    const float* __restrict__ deg,       // [512,5]
    float* __restrict__ out)             // [512,64,81,12]
{
    __shared__ float4 lds4[2][N_L * PITCH_F4];   // out staging, 2 x 25.6 KB
    __shared__ float4 ldsc[2][N_L * CPITCH];     // ctl staging, 2 x 7.2 KB

    const int lane = threadIdx.x & 63;
    const int wave = threadIdx.x >> 6;        // 0 = compute, 1 = writer/loader
    const int b = blockIdx.x;                 // one b per block

    const size_t out_b = (size_t)b * 62208;   // b*64*972 floats

#define FLUSH_SLICE(FBUF, FC, I0, I1)                                             \
    {                                                                             \
        const size_t obase = out_b + 12 + (size_t)(FC) * (SPC * 12);              \
        _Pragma("unroll")                                                         \
        for (int i = (I0); i < (I1); ++i) {                                       \
            const unsigned flat = i * 64 + lane;                                  \
            const unsigned l = flat / 24u;                                        \
            const unsigned q = flat - l * 24u;                                    \
            const float4 v = lds4[FBUF][l * PITCH_F4 + q];                        \
            *reinterpret_cast<float4*>(out + obase + (size_t)l * 972 + q * 4) = v;\
        }                                                                         \
    }

    // writer: coalesced load of chunk CC's controls into ldsc[CBUF].
    // global floats for (b, l, chunk CC): (b*64+l)*240 + CC*24 + j*4, j<6.
#define LOAD_CTL(CBUF, CC)                                                        \
    {                                                                             \
        const size_t gbase = (size_t)b * 15360 + (size_t)(CC) * 24;               \
        _Pragma("unroll")                                                         \
        for (int i = 0; i < 6; ++i) {                                             \
            const unsigned flat = i * 64 + lane;                                  \
            const unsigned l = flat / 6u;                                         \
            const unsigned j = flat - l * 6u;                                     \
            const float4 v = *reinterpret_cast<const float4*>(                    \
                controls + gbase + (size_t)l * 240 + j * 4);                      \
            ldsc[CBUF][l * CPITCH + j] = v;                                       \
        }                                                                         \
    }

    if (wave == 0) {
        // ================= compute persona =================
        const float* dg = deg + b * 5;
        const float steer_scale    = fmaxf(dg[0], 0.05f);
        const float brake_scale    = fmaxf(dg[1], 0.05f);
        const float throttle_scale = fmaxf(dg[2], 0.05f);
        const float friction       = fmaxf(dg[4], 0.1f);

        const float4* x0v = reinterpret_cast<const float4*>(x0 + b * 12);
        const float4 xi0 = x0v[0];
        const float4 xi1 = x0v[1];

        float px  = xi0.x;
        float py  = xi0.y;
        float psi = xi0.z;
        float vx  = xi0.w;
        float vy  = xi1.x;

        const float neg_brake_lim = -7.5f * friction;
        const float yaw_num = friction * 9.81f;
        const float inv_wheelbase = 1.0f / 2.8f;

        __syncthreads();   // prologue: ctl chunk 0 staged by writer

        for (int c = 0; c < NCH; ++c) {
            float4* lrow = &lds4[c & 1][lane * PITCH_F4];
            const float4* crow = &ldsc[c & 1][lane * CPITCH];

            // all 6 ctl f4s for this chunk (b128 reads, conflict-free pitch)
            const float4 u0 = crow[0];
            const float4 u1 = crow[1];
            const float4 u2 = crow[2];
            const float4 u3 = crow[3];
            const float4 u4 = crow[4];
            const float4 u5 = crow[5];

            #pragma unroll
            for (int gg = 0; gg < 2; ++gg) {  // 2 groups of 4 steps
                const float4 c0 = gg ? u3 : u0;
                const float4 c1 = gg ? u4 : u1;
                const float4 c2 = gg ? u5 : u2;

                const Ctl tA = make_ctl(c0.x, c0.y, c0.z, steer_scale, brake_scale, throttle_scale, neg_brake_lim);
                const Ctl tB = make_ctl(c0.w, c1.x, c1.y, steer_scale, brake_scale, throttle_scale, neg_brake_lim);
                const Ctl tC = make_ctl(c1.z, c1.w, c2.x, steer_scale, brake_scale, throttle_scale, neg_brake_lim);
                const Ctl tD = make_ctl(c2.y, c2.z, c2.w, steer_scale, brake_scale, throttle_scale, neg_brake_lim);

#define ROLL_STEP(T, RR)                                                          \
                {                                                                 \
                    const float speed  = __builtin_amdgcn_sqrtf(fmaf(vx, vx, fmaf(vy, vy, 1e-6f))); \
                    const float speed2 = fmaxf(fmaf((T).acc, DT_F, speed), 0.0f); \
                    const float raw_yaw = speed2 * inv_wheelbase * (T).tan_d;     \
                    const float yaw_lim = fmaxf(yaw_num * fast_rcp(fmaxf(speed2, 2.0f)), 0.15f); \
                    const float yaw_rate = fminf(fmaxf(raw_yaw, -1.0f), 1.0f) * yaw_lim; \
                    const float psi2 = fmaf(yaw_rate, DT_F, psi);                 \
                    const float ang = (psi2 + (T).beta) * INV2PI;                 \
                    const float s_ = __builtin_amdgcn_sinf(ang);                  \
                    const float c_ = __builtin_amdgcn_cosf(ang);                  \
                    const float vx2 = speed2 * c_;                                \
                    const float vy2 = speed2 * s_;                                \
                    const float px2 = fmaf(vx2, DT_F, px);                        \
                    const float py2 = fmaf(vy2, DT_F, py);                        \
                    const float ax = (vx2 - vx) * 10.0f;                          \
                    const float ay = (vy2 - vy) * 10.0f;                          \
                    lrow[(RR) * 3 + 0] = make_float4(px2, py2, psi2, vx2);        \
                    lrow[(RR) * 3 + 1] = make_float4(vy2, yaw_rate, ax, ay);      \
                    lrow[(RR) * 3 + 2] = make_float4((T).beta, (T).delta, (T).fb, (T).fx); \
                    px = px2; py = py2; psi = psi2; vx = vx2; vy = vy2;           \
                }

                ROLL_STEP(tA, gg * 4 + 0)
                ROLL_STEP(tB, gg * 4 + 1)
                ROLL_STEP(tC, gg * 4 + 2)
                ROLL_STEP(tD, gg * 4 + 3)
#undef ROLL_STEP
            }
            __syncthreads();   // chunk c staged; ctl for c+1 staged by writer
        }
    } else {
        // ============ writer / control-loader persona ============
        // h = 0 rows (64 l x 3 f4, coalesced-ish, one-time)
        {
            const float4* x0v = reinterpret_cast<const float4*>(x0 + b * 12);
            const float4 xq0 = x0v[0];
            const float4 xq1 = x0v[1];
            const float4 xq2 = x0v[2];
            #pragma unroll
            for (int i = 0; i < 3; ++i) {
                const unsigned flat = i * 64 + lane;
                const unsigned l = flat / 3u;
                const unsigned q = flat - l * 3u;
                const float4 v = (q == 0) ? xq0 : (q == 1) ? xq1 : xq2;
                *reinterpret_cast<float4*>(out + out_b + (size_t)l * 972 + q * 4) = v;
            }
        }
        LOAD_CTL(0, 0)        // stage ctl chunk 0
        __syncthreads();      // prologue barrier

        for (int c = 0; c < NCH; ++c) {
            if (c > 0) FLUSH_SLICE((c - 1) & 1, c - 1, 0, 24)
            if (c + 1 < NCH) LOAD_CTL((c + 1) & 1, c + 1)
            __syncthreads();
        }
        FLUSH_SLICE((NCH - 1) & 1, NCH - 1, 0, 24)
    }
#undef FLUSH_SLICE
#undef LOAD_CTL
}

extern "C" void kernel_launch(void* const* d_in, const int* in_sizes, int n_in,
                              void* d_out, int out_size, void* d_ws, size_t ws_size,
                              hipStream_t stream) {
    (void)in_sizes; (void)n_in; (void)d_ws; (void)ws_size; (void)out_size;
    const float* x0       = (const float*)d_in[0];
    const float* controls = (const float*)d_in[1];
    const float* deg      = (const float*)d_in[2];
    float* out            = (float*)d_out;

    dim3 grid(N_B), block(128);               // 512 blocks x 2 waves
    hipLaunchKernelGGL(degraded_bicycle_rollout_kernel, grid, block, 0, stream,
                       x0, controls, deg, out);
}